// Round 2
// baseline (98.284 us; speedup 1.0000x reference)
//
#include <hip/hip_runtime.h>
#include <hip/hip_bf16.h>
#include <stdint.h>

// ---- types -----------------------------------------------------------------
typedef __bf16 bf16x8 __attribute__((ext_vector_type(8)));
typedef float  f32x4  __attribute__((ext_vector_type(4)));
typedef __attribute__((address_space(1))) const void* gptr_t;
typedef __attribute__((address_space(3))) void*       sptr_t;

#define B_ROWS 8192
#define C_CLS  1000
#define C_PAD  1024
#define P_DIM  512
#define EPS    1e-10f

// ---- workspace layout (bytes) ----------------------------------------------
// [0,            1048576)  means_bf16  [1024][512] bf16  (rows >=1000 zeroed)
// [1048576,      1052672)  m_sq        [1024] f32
// [1052672,      9441280)  xn_bf16     [8192][512] bf16
// [9441280,      9474048)  x_sq        [8192] f32
#define WS_MEANS_BF 0
#define WS_MSQ      1048576
#define WS_XN_BF    1052672
#define WS_XSQ      9441280

// ---- kernel 1: means -> m_sq (f32) + bf16 copy, zero-padded to 1024 rows ---
__global__ __launch_bounds__(64) void prep_means_k(const float* __restrict__ means,
                                                   __hip_bfloat16* __restrict__ means_bf,
                                                   float* __restrict__ m_sq) {
    const int c = blockIdx.x;   // 0..1023
    const int l = threadIdx.x;  // 0..63, one wave per class row
    if (c < C_CLS) {
        const float4* mr = (const float4*)(means + (size_t)c * P_DIM);
        float4 a = mr[l * 2];
        float4 b = mr[l * 2 + 1];
        float s = a.x * a.x + a.y * a.y + a.z * a.z + a.w * a.w
                + b.x * b.x + b.y * b.y + b.z * b.z + b.w * b.w;
        alignas(16) __hip_bfloat16 tmp[8];
        tmp[0] = __float2bfloat16(a.x); tmp[1] = __float2bfloat16(a.y);
        tmp[2] = __float2bfloat16(a.z); tmp[3] = __float2bfloat16(a.w);
        tmp[4] = __float2bfloat16(b.x); tmp[5] = __float2bfloat16(b.y);
        tmp[6] = __float2bfloat16(b.z); tmp[7] = __float2bfloat16(b.w);
        *(uint4*)(means_bf + (size_t)c * P_DIM + l * 8) = *(const uint4*)tmp;
        #pragma unroll
        for (int off = 32; off > 0; off >>= 1) s += __shfl_down(s, off);
        if (l == 0) m_sq[c] = s;
    } else {
        uint4 z = {0u, 0u, 0u, 0u};
        *(uint4*)(means_bf + (size_t)c * P_DIM + l * 8) = z;
        if (l == 0) m_sq[c] = 0.0f;
    }
}

// ---- kernel 2: x rows -> L2-normalized * scale, bf16 + x_sq (f32) ----------
__global__ __launch_bounds__(256) void prep_x_k(const float* __restrict__ x,
                                                const float* __restrict__ m_sq,
                                                __hip_bfloat16* __restrict__ xn_bf,
                                                float* __restrict__ x_sq) {
    const int w = threadIdx.x >> 6;
    const int l = threadIdx.x & 63;
    const int row = blockIdx.x * 4 + w;        // one wave per row
    const float4* xr = (const float4*)(x + (size_t)row * P_DIM);
    float4 a = xr[l * 2];
    float4 b = xr[l * 2 + 1];
    float s = a.x * a.x + a.y * a.y + a.z * a.z + a.w * a.w
            + b.x * b.x + b.y * b.y + b.z * b.z + b.w * b.w;
    #pragma unroll
    for (int off = 32; off > 0; off >>= 1) s += __shfl_down(s, off);
    s = __shfl(s, 0);                          // broadcast sum of squares
    float norm  = sqrtf(s);
    float scale = sqrtf(m_sq[0]);              // ||means[0]||
    float sc    = scale / (norm + EPS);
    alignas(16) __hip_bfloat16 tmp[8];
    tmp[0] = __float2bfloat16(a.x * sc); tmp[1] = __float2bfloat16(a.y * sc);
    tmp[2] = __float2bfloat16(a.z * sc); tmp[3] = __float2bfloat16(a.w * sc);
    tmp[4] = __float2bfloat16(b.x * sc); tmp[5] = __float2bfloat16(b.y * sc);
    tmp[6] = __float2bfloat16(b.z * sc); tmp[7] = __float2bfloat16(b.w * sc);
    *(uint4*)(xn_bf + (size_t)row * P_DIM + l * 8) = *(const uint4*)tmp;
    if (l == 0) {
        float sn = sc * norm;                  // ||xn|| exactly as reference computes it
        x_sq[row] = sn * sn;
    }
}

// ---- kernel 3: logits = 2*(xn @ means^T) - x_sq - m_sq ---------------------
// 128x128 block tile, BK=32, 4 waves (2x2), each wave 64x64 via 4x4 mfma 16x16x32.
// ONE mfma k-step per staged BK=32 tile: the instruction consumes K=32
// (A[m=lane&15][k=quad*8+j], quads cover k=0..31 = the full 64-byte LDS row).
// LDS: A tile [128][32] bf16 @0 (8 KB), B tile [128][32] bf16 @8192 (8 KB), no pad
// (global_load_lds requires contiguous wave-uniform-base + lane*16 layout;
// row stride 64 B -> 2-way bank aliasing on ds_read_b128, free per m136).
__global__ __launch_bounds__(256) void gemm_k(const __hip_bfloat16* __restrict__ A,   // xn   [8192][512]
                                              const __hip_bfloat16* __restrict__ B,   // means[1024][512]
                                              const float* __restrict__ x_sq,
                                              const float* __restrict__ m_sq,
                                              float* __restrict__ out) {
    __shared__ alignas(16) char lds[16384];
    const int t  = threadIdx.x;
    const int w  = t >> 6;          // wave 0..3
    const int l  = t & 63;
    const int wr = w >> 1;          // wave row 0..1
    const int wc = w & 1;           // wave col 0..1
    const int q   = l >> 4;         // quad 0..3
    const int m16 = l & 15;

    const int brow = blockIdx.y;    // 0..63
    const int bcol = blockIdx.x;    // 0..7

    f32x4 acc[4][4];
    #pragma unroll
    for (int i = 0; i < 4; ++i)
        #pragma unroll
        for (int j = 0; j < 4; ++j) {
            f32x4 z = {0.f, 0.f, 0.f, 0.f};
            acc[i][j] = z;
        }

    const char* Abase = (const char*)A + (size_t)(brow * 128) * (P_DIM * 2);
    const char* Bbase = (const char*)B + (size_t)(bcol * 128) * (P_DIM * 2);

    for (int k0 = 0; k0 < P_DIM; k0 += 32) {
        // ---- stage: 2 tiles x 8192 B; each round = 256 thr x 16 B = 4096 B
        #pragma unroll
        for (int r = 0; r < 2; ++r) {
            const int o    = r * 4096 + t * 16;   // linear byte offset in tile
            const int trow = o >> 6;              // tile row (64 B per row)
            const int kb   = o & 63;              // byte within the 32-elem k chunk
            const char* gA = Abase + (size_t)trow * (P_DIM * 2) + k0 * 2 + kb;
            const char* gB = Bbase + (size_t)trow * (P_DIM * 2) + k0 * 2 + kb;
            // wave-uniform LDS base; HW adds lane*16
            char* dA = lds + r * 4096 + w * 1024;
            char* dB = lds + 8192 + r * 4096 + w * 1024;
            __builtin_amdgcn_global_load_lds((gptr_t)gA, (sptr_t)dA, 16, 0, 0);
            __builtin_amdgcn_global_load_lds((gptr_t)gB, (sptr_t)dB, 16, 0, 0);
        }
        __syncthreads();

        // ---- compute: one K=32 mfma step over the staged tile
        bf16x8 af[4], bfr[4];
        #pragma unroll
        for (int i = 0; i < 4; ++i) {
            const int m = wr * 64 + i * 16 + m16;
            af[i] = *(const bf16x8*)(lds + m * 64 + q * 16);
        }
        #pragma unroll
        for (int j = 0; j < 4; ++j) {
            const int n = wc * 64 + j * 16 + m16;
            bfr[j] = *(const bf16x8*)(lds + 8192 + n * 64 + q * 16);
        }
        #pragma unroll
        for (int i = 0; i < 4; ++i)
            #pragma unroll
            for (int j = 0; j < 4; ++j)
                acc[i][j] = __builtin_amdgcn_mfma_f32_16x16x32_bf16(af[i], bfr[j], acc[i][j], 0, 0, 0);
        __syncthreads();
    }

    // ---- epilogue: out = 2*cross - x_sq[row] - m_sq[col]; C/D layout:
    // col = lane&15, row = quad*4 + reg  [verified mapping, m89/m91]
    const int rowbase = brow * 128 + wr * 64;
    const int colbase = bcol * 128 + wc * 64;
    float msq[4];
    #pragma unroll
    for (int j = 0; j < 4; ++j) {
        const int col = colbase + j * 16 + m16;
        msq[j] = (col < C_CLS) ? m_sq[col] : 0.0f;
    }
    #pragma unroll
    for (int i = 0; i < 4; ++i) {
        #pragma unroll
        for (int reg = 0; reg < 4; ++reg) {
            const int row = rowbase + i * 16 + q * 4 + reg;
            const float xsq = x_sq[row];
            #pragma unroll
            for (int j = 0; j < 4; ++j) {
                const int col = colbase + j * 16 + m16;
                if (col < C_CLS) {
                    out[(size_t)row * C_CLS + col] = 2.0f * acc[i][j][reg] - xsq - msq[j];
                }
            }
        }
    }
}

// ---- launch ----------------------------------------------------------------
extern "C" void kernel_launch(void* const* d_in, const int* in_sizes, int n_in,
                              void* d_out, int out_size, void* d_ws, size_t ws_size,
                              hipStream_t stream) {
    const float* x     = (const float*)d_in[0];   // [8192][512]
    const float* means = (const float*)d_in[1];   // [1000][512]
    float* out = (float*)d_out;                   // [8192][1000]
    char* ws = (char*)d_ws;

    __hip_bfloat16* means_bf = (__hip_bfloat16*)(ws + WS_MEANS_BF);
    float*          m_sq     = (float*)(ws + WS_MSQ);
    __hip_bfloat16* xn_bf    = (__hip_bfloat16*)(ws + WS_XN_BF);
    float*          x_sq     = (float*)(ws + WS_XSQ);

    prep_means_k<<<C_PAD, 64, 0, stream>>>(means, means_bf, m_sq);
    prep_x_k<<<B_ROWS / 4, 256, 0, stream>>>(x, m_sq, xn_bf, x_sq);
    gemm_k<<<dim3(C_PAD / 128, B_ROWS / 128), 256, 0, stream>>>(xn_bf, means_bf, x_sq, m_sq, out);
}

// Round 3
// 95.483 us; speedup vs baseline: 1.0293x; 1.0293x over previous
//
#include <hip/hip_runtime.h>
#include <hip/hip_bf16.h>
#include <stdint.h>

// ---- types -----------------------------------------------------------------
typedef __bf16 bf16x8 __attribute__((ext_vector_type(8)));
typedef float  f32x4  __attribute__((ext_vector_type(4)));
typedef __attribute__((address_space(1))) const void* gptr_t;
typedef __attribute__((address_space(3))) void*       sptr_t;

#define B_ROWS 8192
#define C_CLS  1000
#define C_PAD  1024
#define P_DIM  512
#define EPS    1e-10f

// ---- workspace layout (bytes) ----------------------------------------------
// [0,            1048576)  means_bf16  [1024][512] bf16  (rows >=1000 zeroed)
// [1048576,      1052672)  m_sq        [1024] f32
// [1052672,      9441280)  xn_bf16     [8192][512] bf16
// [9441280,      9474048)  x_sq        [8192] f32
#define WS_MEANS_BF 0
#define WS_MSQ      1048576
#define WS_XN_BF    1052672
#define WS_XSQ      9441280

__device__ __forceinline__ float dot8(float4 a, float4 b) {
    return a.x * a.x + a.y * a.y + a.z * a.z + a.w * a.w
         + b.x * b.x + b.y * b.y + b.z * b.z + b.w * b.w;
}

// ---- kernel 1 (fused prep): blocks 0..2047 -> x rows; 2048..2303 -> means ---
// x-waves compute scale = ||means[0]|| themselves (2 KB L2-hot read/wave),
// removing the inter-kernel dependency that forced 3 serialized dispatches.
__global__ __launch_bounds__(256) void prep_k(const float* __restrict__ x,
                                              const float* __restrict__ means,
                                              __hip_bfloat16* __restrict__ means_bf,
                                              float* __restrict__ m_sq,
                                              __hip_bfloat16* __restrict__ xn_bf,
                                              float* __restrict__ x_sq) {
    const int w = threadIdx.x >> 6;
    const int l = threadIdx.x & 63;
    const int bid = blockIdx.x;

    if (bid < B_ROWS / 4) {
        // ---- x row: one wave per row
        const int row = bid * 4 + w;
        // scale from means row 0 (pristine input, L2-hot)
        const float4* m0 = (const float4*)means;
        float4 ma = m0[l * 2];
        float4 mb = m0[l * 2 + 1];
        float ms = dot8(ma, mb);
        const float4* xr = (const float4*)(x + (size_t)row * P_DIM);
        float4 a = xr[l * 2];
        float4 b = xr[l * 2 + 1];
        float s = dot8(a, b);
        #pragma unroll
        for (int off = 32; off > 0; off >>= 1) {
            ms += __shfl_down(ms, off);
            s  += __shfl_down(s, off);
        }
        ms = __shfl(ms, 0);
        s  = __shfl(s, 0);
        float scale = sqrtf(ms);               // ||means[0]||
        float norm  = sqrtf(s);
        float sc    = scale / (norm + EPS);
        alignas(16) __hip_bfloat16 tmp[8];
        tmp[0] = __float2bfloat16(a.x * sc); tmp[1] = __float2bfloat16(a.y * sc);
        tmp[2] = __float2bfloat16(a.z * sc); tmp[3] = __float2bfloat16(a.w * sc);
        tmp[4] = __float2bfloat16(b.x * sc); tmp[5] = __float2bfloat16(b.y * sc);
        tmp[6] = __float2bfloat16(b.z * sc); tmp[7] = __float2bfloat16(b.w * sc);
        *(uint4*)(xn_bf + (size_t)row * P_DIM + l * 8) = *(const uint4*)tmp;
        if (l == 0) {
            float sn = sc * norm;              // ||xn|| as the reference computes it
            x_sq[row] = sn * sn;
        }
    } else {
        // ---- means row: one wave per class (padded to 1024)
        const int c = (bid - B_ROWS / 4) * 4 + w;
        if (c < C_CLS) {
            const float4* mr = (const float4*)(means + (size_t)c * P_DIM);
            float4 a = mr[l * 2];
            float4 b = mr[l * 2 + 1];
            float s = dot8(a, b);
            alignas(16) __hip_bfloat16 tmp[8];
            tmp[0] = __float2bfloat16(a.x); tmp[1] = __float2bfloat16(a.y);
            tmp[2] = __float2bfloat16(a.z); tmp[3] = __float2bfloat16(a.w);
            tmp[4] = __float2bfloat16(b.x); tmp[5] = __float2bfloat16(b.y);
            tmp[6] = __float2bfloat16(b.z); tmp[7] = __float2bfloat16(b.w);
            *(uint4*)(means_bf + (size_t)c * P_DIM + l * 8) = *(const uint4*)tmp;
            #pragma unroll
            for (int off = 32; off > 0; off >>= 1) s += __shfl_down(s, off);
            if (l == 0) m_sq[c] = s;
        } else {
            uint4 z = {0u, 0u, 0u, 0u};
            *(uint4*)(means_bf + (size_t)c * P_DIM + l * 8) = z;
            if (l == 0) m_sq[c] = 0.0f;
        }
    }
}

// ---- kernel 2: logits = 2*(xn @ means^T) - x_sq - m_sq ---------------------
// 64x128 block tile, BK=32, grid 128x8 = 1024 blocks (4 blocks/CU, 16 waves/CU
// vs 2 blocks/8 waves at 128x128 -- occupancy was the R2 bottleneck theory).
// 4 waves; wave w computes all 64 rows x cols [w*32, w*32+32) via 4x2 mfma
// 16x16x32 (32 acc VGPRs). LDS: A[64][32] @0 (4 KB), B[128][32] @4096 (8 KB).
// Row stride 64 B; one K=32 mfma step consumes the full row (quads cover k).
__global__ __launch_bounds__(256, 4) void gemm_k(const __hip_bfloat16* __restrict__ A,   // xn   [8192][512]
                                                 const __hip_bfloat16* __restrict__ B,   // means[1024][512]
                                                 const float* __restrict__ x_sq,
                                                 const float* __restrict__ m_sq,
                                                 float* __restrict__ out) {
    __shared__ alignas(16) char lds[12288];
    const int t   = threadIdx.x;
    const int w   = t >> 6;         // wave 0..3
    const int l   = t & 63;
    const int q   = l >> 4;         // quad 0..3
    const int m16 = l & 15;

    const int brow = blockIdx.y;    // 0..127 (64-row tiles)
    const int bcol = blockIdx.x;    // 0..7   (128-col tiles)

    f32x4 acc[4][2];
    #pragma unroll
    for (int i = 0; i < 4; ++i)
        #pragma unroll
        for (int j = 0; j < 2; ++j) {
            f32x4 z = {0.f, 0.f, 0.f, 0.f};
            acc[i][j] = z;
        }

    const char* Abase = (const char*)A + (size_t)(brow * 64)  * (P_DIM * 2);
    const char* Bbase = (const char*)B + (size_t)(bcol * 128) * (P_DIM * 2);

    for (int k0 = 0; k0 < P_DIM; k0 += 32) {
        // ---- stage 12 KB: A tile 4 KB (round 0) + B tile 8 KB (rounds 1,2).
        // Wave-uniform LDS base (wbase); HW adds lane*16.
        #pragma unroll
        for (int r = 0; r < 3; ++r) {
            const int wbase = r * 4096 + w * 1024;   // wave-uniform
            const int o     = wbase + l * 16;
            const char* g;
            if (r == 0) {  // A region: o in [0,4096), row = o>>6
                g = Abase + (size_t)(o >> 6) * (P_DIM * 2) + k0 * 2 + (o & 63);
            } else {       // B region: o' = o-4096 in [0,8192), row = o'>>6
                const int o2 = o - 4096;
                g = Bbase + (size_t)(o2 >> 6) * (P_DIM * 2) + k0 * 2 + (o2 & 63);
            }
            __builtin_amdgcn_global_load_lds((gptr_t)g, (sptr_t)(lds + wbase), 16, 0, 0);
        }
        __syncthreads();

        // ---- one K=32 mfma step over the staged tile
        bf16x8 af[4], bfr[2];
        #pragma unroll
        for (int i = 0; i < 4; ++i) {
            const int m = i * 16 + m16;
            af[i] = *(const bf16x8*)(lds + m * 64 + q * 16);
        }
        #pragma unroll
        for (int j = 0; j < 2; ++j) {
            const int n = w * 32 + j * 16 + m16;
            bfr[j] = *(const bf16x8*)(lds + 4096 + n * 64 + q * 16);
        }
        #pragma unroll
        for (int i = 0; i < 4; ++i)
            #pragma unroll
            for (int j = 0; j < 2; ++j)
                acc[i][j] = __builtin_amdgcn_mfma_f32_16x16x32_bf16(af[i], bfr[j], acc[i][j], 0, 0, 0);
        __syncthreads();
    }

    // ---- epilogue: out = 2*cross - x_sq[row] - m_sq[col]
    // C/D layout: col = lane&15, row = quad*4 + reg [verified m89/m91 + R2 pass]
    const int rowbase = brow * 64;
    const int colbase = bcol * 128 + w * 32;
    float msq[2];
    #pragma unroll
    for (int j = 0; j < 2; ++j) {
        const int col = colbase + j * 16 + m16;
        msq[j] = (col < C_CLS) ? m_sq[col] : 0.0f;
    }
    #pragma unroll
    for (int i = 0; i < 4; ++i) {
        #pragma unroll
        for (int reg = 0; reg < 4; ++reg) {
            const int row = rowbase + i * 16 + q * 4 + reg;
            const float xsq = x_sq[row];
            #pragma unroll
            for (int j = 0; j < 2; ++j) {
                const int col = colbase + j * 16 + m16;
                if (col < C_CLS) {
                    out[(size_t)row * C_CLS + col] = 2.0f * acc[i][j][reg] - xsq - msq[j];
                }
            }
        }
    }
}

// ---- launch ----------------------------------------------------------------
extern "C" void kernel_launch(void* const* d_in, const int* in_sizes, int n_in,
                              void* d_out, int out_size, void* d_ws, size_t ws_size,
                              hipStream_t stream) {
    const float* x     = (const float*)d_in[0];   // [8192][512]
    const float* means = (const float*)d_in[1];   // [1000][512]
    float* out = (float*)d_out;                   // [8192][1000]
    char* ws = (char*)d_ws;

    __hip_bfloat16* means_bf = (__hip_bfloat16*)(ws + WS_MEANS_BF);
    float*          m_sq     = (float*)(ws + WS_MSQ);
    __hip_bfloat16* xn_bf    = (__hip_bfloat16*)(ws + WS_XN_BF);
    float*          x_sq     = (float*)(ws + WS_XSQ);

    prep_k<<<B_ROWS / 4 + C_PAD / 4, 256, 0, stream>>>(x, means, means_bf, m_sq, xn_bf, x_sq);
    gemm_k<<<dim3(C_PAD / 128, B_ROWS / 64), 256, 0, stream>>>(xn_bf, means_bf, x_sq, m_sq, out);
}